// Round 20
// baseline (903.640 us; speedup 1.0000x reference)
//
#include <hip/hip_runtime.h>

#define MDIM 8192   // B*S
#define KDIM 4096   // DIN
#define NDIM 11008  // DOUT

#define NBLK_W 1024

typedef float f32x4 __attribute__((ext_vector_type(4)));
typedef int   i32x4 __attribute__((ext_vector_type(4)));
typedef char  c4    __attribute__((ext_vector_type(4)));

#define GAS __attribute__((address_space(1)))
#define LAS __attribute__((address_space(3)))

// --- Kernel 1: sign(W) -> {-1,0,+1} i8, fused with |W| partial reduction ---
__global__ __launch_bounds__(256) void k_convert_w(const float* __restrict__ w,
                                                   char* __restrict__ wq,
                                                   float* __restrict__ partials) {
  const int n4 = (NDIM * KDIM) / 4;
  const int stride = gridDim.x * blockDim.x;
  float s = 0.f;
  for (int i = blockIdx.x * blockDim.x + threadIdx.x; i < n4; i += stride) {
    f32x4 v = ((const f32x4*)w)[i];
    s += fabsf(v.x) + fabsf(v.y) + fabsf(v.z) + fabsf(v.w);
    c4 q;
    q.x = v.x > 0.f ? 1 : (v.x < 0.f ? -1 : 0);
    q.y = v.y > 0.f ? 1 : (v.y < 0.f ? -1 : 0);
    q.z = v.z > 0.f ? 1 : (v.z < 0.f ? -1 : 0);
    q.w = v.w > 0.f ? 1 : (v.w < 0.f ? -1 : 0);
    ((c4*)wq)[i] = q;
  }
  #pragma unroll
  for (int off = 32; off > 0; off >>= 1) s += __shfl_down(s, off, 64);
  __shared__ float red[4];
  if ((threadIdx.x & 63) == 0) red[threadIdx.x >> 6] = s;
  __syncthreads();
  if (threadIdx.x == 0) partials[blockIdx.x] = red[0] + red[1] + red[2] + red[3];
}

// --- Kernel 2: deterministic final reduction -> scale_w = mean|W| ---
__global__ __launch_bounds__(256) void k_scale(const float* __restrict__ partials,
                                               float* __restrict__ scale) {
  float s = 0.f;
  for (int i = threadIdx.x; i < NBLK_W; i += 256) s += partials[i];
  #pragma unroll
  for (int off = 32; off > 0; off >>= 1) s += __shfl_down(s, off, 64);
  __shared__ float red[4];
  if ((threadIdx.x & 63) == 0) red[threadIdx.x >> 6] = s;
  __syncthreads();
  if (threadIdx.x == 0)
    *scale = (red[0] + red[1] + red[2] + red[3]) / (float)((size_t)NDIM * KDIM);
}

// --- Kernel 3: x fp32 -> i8 with per-row scale s_x[m] = max|x[m,:]|/127 ---
__global__ __launch_bounds__(256) void k_convert_x(const float* __restrict__ x,
                                                   char* __restrict__ xq,
                                                   float* __restrict__ sx) {
  const int row = blockIdx.x;
  const float* xr = x + (size_t)row * KDIM;
  const int t = (int)threadIdx.x;
  f32x4 v[4];
  float mx = 0.f;
  #pragma unroll
  for (int j = 0; j < 4; ++j) {
    v[j] = *(const f32x4*)(xr + j * 1024 + t * 4);
    mx = fmaxf(mx, fmaxf(fmaxf(fabsf(v[j].x), fabsf(v[j].y)),
                         fmaxf(fabsf(v[j].z), fabsf(v[j].w))));
  }
  #pragma unroll
  for (int off = 32; off > 0; off >>= 1) mx = fmaxf(mx, __shfl_xor(mx, off, 64));
  __shared__ float red[4];
  __shared__ float bmax;
  if ((t & 63) == 0) red[t >> 6] = mx;
  __syncthreads();
  if (t == 0) {
    float m2 = fmaxf(fmaxf(red[0], red[1]), fmaxf(red[2], red[3]));
    m2 = fmaxf(m2, 1e-20f);
    bmax = m2;
    sx[row] = m2 * (1.f / 127.f);
  }
  __syncthreads();
  const float r = 127.f / bmax;
  #pragma unroll
  for (int j = 0; j < 4; ++j) {
    int a = __float2int_rn(v[j].x * r), b = __float2int_rn(v[j].y * r);
    int c = __float2int_rn(v[j].z * r), d = __float2int_rn(v[j].w * r);
    a = a > 127 ? 127 : (a < -127 ? -127 : a);
    b = b > 127 ? 127 : (b < -127 ? -127 : b);
    c = c > 127 ? 127 : (c < -127 ? -127 : c);
    d = d > 127 ? 127 : (d < -127 ? -127 : d);
    c4 q; q.x = (char)a; q.y = (char)b; q.z = (char)c; q.w = (char)d;
    *(c4*)(xq + (size_t)row * KDIM + j * 1024 + t * 4) = q;
  }
}

// --- Kernel 4: 128x256 i8 GEMM, A-only LDS (B direct from global/L2) ---
// C[m][n] = scale_w * sx[m] * (sum_k xq[m][k]*wq[n][k]) + bias[n]
// vs r17 (417us; LDS 88KB/blk-Ktile ~ binding pipe): move B frags to DIRECT
// global loads (per-lane 16B gather, each 64B line fully consumed; wq L3-
// resident + supertile L2 reuse, dup only 2x). LDS traffic 88->40KB/blk-Ktile
// (A reads 32 + A stage 8); LDS buffers 3x8KB (A only). 2 phases/K-tile.
//   P0: 8 MFMA (afL x bq01,bq23); LDS-read afH(bc); BAR
//   P1: 8 MFMA (afH x bq01,bq23); GLOBAL bq4<-K_{i+1} (WAR after MFMA); SB0;
//       stage A(bs)<-K_{i+2}; VM(5); LDS-read afL(bn); BAR
// VMEM ledger (order bq4 then stA keeps stage depth): steady outstanding
//   entering i = {i-1.bq4(4), i-1.stA(1)}. i.P0 MFMA: compiler vmcnt(1)
//   retires i-1.bq4 (age 2 phases). i.P1 VM(5): outstanding = i-1.stA +
//   i.bq4 + i.stA = 6 -> retires i-1.stA (age 2 phases ~800-1200cyc) so
//   bn.A is landed before its LDS read. Never full-drain in loop.
// WAR: stA(K_{i+2}) overwrites buffer of K_{i-1}; its readers (af) issued
//   <= i-1.P0 and consumed by i-1.P1 MFMAs -> >=1 barrier before stage.
//   bq reload P1 SB0-pinned after afH MFMAs (last use of bq(K_i)).
//   af reloads WAR-pinned after the MFMAs consuming the old half.
// A frag layout + 3-bit swizzle + supertile grid: r13/r17-verified unchanged.
// B frag from global = same bytes the LDS path delivered (swizzle cancels).
// Registers: acc 64 AGPR + af16 + bq16 + addr ~25 -> target <=64 arch VGPR
//   (if VGPR>64 -> occupancy fail -> revert r17).
// (r19 fix: MFMA4 macro params parenthesized -- `af + 2[mi]` precedence bug.)

#define BAR()  __builtin_amdgcn_s_barrier()
#define SB0()  __builtin_amdgcn_sched_barrier(0)
#define PRIO1() __builtin_amdgcn_s_setprio(1)
#define PRIO0() __builtin_amdgcn_s_setprio(0)
#define VM(N)  asm volatile("s_waitcnt vmcnt(" #N ")" ::: "memory")

// One 8KB A half-tile: 128 rows x 64 B; LDSOFF runtime
#define STAGE_A(LDSOFF, KT) do {                                                      \
  const char* _s = A + (size_t)(aRow + srow) * KDIM + (KT)*64 + scol;                 \
  char* _d = lds + (LDSOFF) + tid*16;                                                 \
  __builtin_amdgcn_global_load_lds((const GAS unsigned int*)_s,                       \
                                   (LAS unsigned int*)_d, 16, 0, 0);                  \
} while (0)

// A frag pair from LDS: DST[0..1] covers rows wm*64 + MH*32 + mi*16 + l15
#define LOAD_A2(DST, BASE, MH)                                                        \
  _Pragma("unroll") for (int mi = 0; mi < 2; ++mi)                                    \
    (DST)[mi] = *(const i32x4*)&lds[(BASE) + aWOff + (MH)*2048 + mi*1024              \
                                    + rowoff + rcol];

// B frags direct from global: rows bRow + wn*64 + {0,16,32,48} + l15
#define LOADG_B(KT) do {                                                              \
  _Pragma("unroll") for (int ni = 0; ni < 2; ++ni) {                                  \
    bq01[ni] = *(const i32x4*)(bgp + (size_t)(ni * 16) * KDIM + (size_t)(KT) * 64);   \
    bq23[ni] = *(const i32x4*)(bgp + (size_t)((ni + 2) * 16) * KDIM + (size_t)(KT) * 64); \
  }                                                                                   \
} while (0)

// 4 MFMA (16x16x64 i8): 2 mi x 2 ni -> acc[MB+mi][NB+ni]
#define MFMA4(AF, MB, BQ, NB)                                                         \
  _Pragma("unroll") for (int mi = 0; mi < 2; ++mi)                                    \
  _Pragma("unroll") for (int ni = 0; ni < 2; ++ni)                                    \
    acc[(MB)+mi][(NB)+ni] = __builtin_amdgcn_mfma_i32_16x16x64_i8(                    \
        (AF)[mi], (BQ)[ni], acc[(MB)+mi][(NB)+ni], 0, 0, 0);

__global__ __launch_bounds__(512, 4) void k_gemm256(const char* __restrict__ A,
                                                    const char* __restrict__ B,
                                                    const float* __restrict__ bias,
                                                    const float* __restrict__ sx,
                                                    const float* __restrict__ scale_p,
                                                    float* __restrict__ C) {
  extern __shared__ char lds[];

  const int nTn = NDIM / 256;                  // 43
  const int nwg = (MDIM / 128) * nTn;          // 2752 (== 0 mod 8)
  int wg = (int)blockIdx.x;
  wg = (wg & 7) * (nwg / 8) + (wg >> 3);       // XCD-aware swizzle (bijective)
  // 8x8 super-tile order within each XCD band (L2 panel reuse)
  const int band = wg / (nTn * 8);             // 0..7
  const int rem  = wg % (nTn * 8);             // 0..343
  const int tn   = rem >> 3;                   // 0..42
  const int tm   = band * 8 + (rem & 7);       // 0..63

  const int tid  = (int)threadIdx.x;
  const int lane = tid & 63;
  const int wave = tid >> 6;                   // 0..7
  const int wm   = wave >> 2;                  // 0..1  (M)
  const int wn   = wave & 3;                   // 0..3  (N)
  const int l15  = lane & 15;

  // LDS A read-side (r13/r17-verified): row = l15 (+16-mults), swizzled col
  const int rowoff = l15 * 64;
  const int rcol = ((lane >> 4) << 4) ^ (((l15 >> 1) & 3) << 4);
  // stage-side (verified involution): linear LDS dest; pre-swizzled global col
  const int srow = tid >> 2;                   // 0..127
  const int scol = ((tid & 3) << 4) ^ (((tid >> 3) & 3) << 4);

  const int aWOff = wm * 4096;                 // this wave's 64 A-rows (bytes)
  const int aRow = tm * 128;
  const int bRow = tn * 256;

  // per-lane global B base: row = bRow + wn*64 + l15, k-sub = (lane>>4)*16
  const char* bgp = B + (size_t)(bRow + wn * 64 + l15) * KDIM + ((lane >> 4) << 4);

  i32x4 acc[4][4];
  #pragma unroll
  for (int i = 0; i < 4; ++i)
    #pragma unroll
    for (int j = 0; j < 4; ++j) acc[i][j] = i32x4{0, 0, 0, 0};

  i32x4 af[4], bq01[2], bq23[2];

  int b_c = 0, b_n = 8192, b_s = 16384;        // compute / next / stage bases

  // ---- prologue: bq(K0); A(b0)<-K0; A(b1)<-K1; VM(1); afL(b0) ----
  LOADG_B(0);
  SB0();
  STAGE_A(0,    0);
  STAGE_A(8192, 1);
  VM(1);                                       // retires bq(K0)+b0 stage; b1 in flight
  SB0();
  BAR();
  LOAD_A2(af, 0, 0);                           // afL (K0)

  #pragma unroll 1
  for (int i = 0; i < 64; ++i) {
    const int kB = (i + 1 > 63) ? 63 : i + 1;  // clamped tail
    const int kS = (i + 2 > 63) ? 63 : i + 2;
    // P0: 8 MFMA (afL x bq01,bq23)@K_i; LDS-read afH(bc)
    PRIO1(); MFMA4(af, 0, bq01, 0); MFMA4(af, 0, bq23, 2); PRIO0(); SB0();
    LOAD_A2(af + 2, b_c, 1);
    BAR();
    // P1: 8 MFMA (afH x bq01,bq23); bq4<-K_{i+1} (global, WAR-pinned); stage
    //     A(bs)<-K_{i+2}; VM(5) lands bn; LDS-read afL(bn)
    PRIO1(); MFMA4(af + 2, 2, bq01, 0); MFMA4(af + 2, 2, bq23, 2); PRIO0(); SB0();
    LOADG_B(kB);
    SB0();
    STAGE_A(b_s, kS);
    VM(5); SB0();
    LOAD_A2(af, b_n, 0);
    BAR();
    // rotate buffers
    const int t = b_c; b_c = b_n; b_n = b_s; b_s = t;
  }

  VM(0);  // drain tail ops before epilogue

  const float sc = *scale_p;
  float bv[4];
  #pragma unroll
  for (int ni = 0; ni < 4; ++ni) bv[ni] = bias[tn * 256 + wn * 64 + ni * 16 + l15];

  // C/D layout (dtype-independent): col = lane&15, row = (lane>>4)*4 + reg
  #pragma unroll
  for (int mi = 0; mi < 4; ++mi) {
    #pragma unroll
    for (int r = 0; r < 4; ++r) {
      const int m = tm * 128 + wm * 64 + mi * 16 + (lane >> 4) * 4 + r;
      const float srow_scale = sc * sx[m];
      float* crow = C + (size_t)m * NDIM + tn * 256 + wn * 64;
      #pragma unroll
      for (int ni = 0; ni < 4; ++ni)
        crow[ni * 16 + l15] = srow_scale * (float)acc[mi][ni][r] + bv[ni];
    }
  }
}

extern "C" void kernel_launch(void* const* d_in, const int* in_sizes, int n_in,
                              void* d_out, int out_size, void* d_ws, size_t ws_size,
                              hipStream_t stream) {
  const float* x = (const float*)d_in[0];
  const float* w = (const float*)d_in[1];
  const float* bias = (const float*)d_in[2];
  float* out = (float*)d_out;

  char* ws = (char*)d_ws;
  const size_t XQ_BYTES = (size_t)MDIM * KDIM;   // 33,554,432
  const size_t WQ_BYTES = (size_t)NDIM * KDIM;   // 45,088,768
  char* xq = ws;
  char* wq = ws + XQ_BYTES;
  float* sx = (float*)(ws + XQ_BYTES + WQ_BYTES);
  float* partials = sx + MDIM;
  float* scale = partials + NBLK_W;

  k_convert_w<<<NBLK_W, 256, 0, stream>>>(w, wq, partials);
  k_scale<<<1, 256, 0, stream>>>(partials, scale);
  k_convert_x<<<MDIM, 256, 0, stream>>>(x, xq, sx);

  (void)hipFuncSetAttribute((const void*)k_gemm256,
                            hipFuncAttributeMaxDynamicSharedMemorySize, 24576);
  const int grid = (MDIM / 128) * (NDIM / 256);  // 2752
  k_gemm256<<<grid, 512, 24576, stream>>>(xq, wq, bias, sx, scale, out);
}

// Round 21
// 503.168 us; speedup vs baseline: 1.7959x; 1.7959x over previous
//
#include <hip/hip_runtime.h>

#define MDIM 8192   // B*S
#define KDIM 4096   // DIN
#define NDIM 11008  // DOUT

#define NBLK_W 1024

typedef float f32x4 __attribute__((ext_vector_type(4)));
typedef int   i32x4 __attribute__((ext_vector_type(4)));
typedef char  c4    __attribute__((ext_vector_type(4)));

#define GAS __attribute__((address_space(1)))
#define LAS __attribute__((address_space(3)))

// --- Kernel 1: sign(W) -> {-1,0,+1} i8, fused with |W| partial reduction ---
__global__ __launch_bounds__(256) void k_convert_w(const float* __restrict__ w,
                                                   char* __restrict__ wq,
                                                   float* __restrict__ partials) {
  const int n4 = (NDIM * KDIM) / 4;
  const int stride = gridDim.x * blockDim.x;
  float s = 0.f;
  for (int i = blockIdx.x * blockDim.x + threadIdx.x; i < n4; i += stride) {
    f32x4 v = ((const f32x4*)w)[i];
    s += fabsf(v.x) + fabsf(v.y) + fabsf(v.z) + fabsf(v.w);
    c4 q;
    q.x = v.x > 0.f ? 1 : (v.x < 0.f ? -1 : 0);
    q.y = v.y > 0.f ? 1 : (v.y < 0.f ? -1 : 0);
    q.z = v.z > 0.f ? 1 : (v.z < 0.f ? -1 : 0);
    q.w = v.w > 0.f ? 1 : (v.w < 0.f ? -1 : 0);
    ((c4*)wq)[i] = q;
  }
  #pragma unroll
  for (int off = 32; off > 0; off >>= 1) s += __shfl_down(s, off, 64);
  __shared__ float red[4];
  if ((threadIdx.x & 63) == 0) red[threadIdx.x >> 6] = s;
  __syncthreads();
  if (threadIdx.x == 0) partials[blockIdx.x] = red[0] + red[1] + red[2] + red[3];
}

// --- Kernel 2: deterministic final reduction -> scale_w = mean|W| ---
__global__ __launch_bounds__(256) void k_scale(const float* __restrict__ partials,
                                               float* __restrict__ scale) {
  float s = 0.f;
  for (int i = threadIdx.x; i < NBLK_W; i += 256) s += partials[i];
  #pragma unroll
  for (int off = 32; off > 0; off >>= 1) s += __shfl_down(s, off, 64);
  __shared__ float red[4];
  if ((threadIdx.x & 63) == 0) red[threadIdx.x >> 6] = s;
  __syncthreads();
  if (threadIdx.x == 0)
    *scale = (red[0] + red[1] + red[2] + red[3]) / (float)((size_t)NDIM * KDIM);
}

// --- Kernel 3: x fp32 -> i8 with per-row scale s_x[m] = max|x[m,:]|/127 ---
__global__ __launch_bounds__(256) void k_convert_x(const float* __restrict__ x,
                                                   char* __restrict__ xq,
                                                   float* __restrict__ sx) {
  const int row = blockIdx.x;
  const float* xr = x + (size_t)row * KDIM;
  const int t = (int)threadIdx.x;
  f32x4 v[4];
  float mx = 0.f;
  #pragma unroll
  for (int j = 0; j < 4; ++j) {
    v[j] = *(const f32x4*)(xr + j * 1024 + t * 4);
    mx = fmaxf(mx, fmaxf(fmaxf(fabsf(v[j].x), fabsf(v[j].y)),
                         fmaxf(fabsf(v[j].z), fabsf(v[j].w))));
  }
  #pragma unroll
  for (int off = 32; off > 0; off >>= 1) mx = fmaxf(mx, __shfl_xor(mx, off, 64));
  __shared__ float red[4];
  __shared__ float bmax;
  if ((t & 63) == 0) red[t >> 6] = mx;
  __syncthreads();
  if (t == 0) {
    float m2 = fmaxf(fmaxf(red[0], red[1]), fmaxf(red[2], red[3]));
    m2 = fmaxf(m2, 1e-20f);
    bmax = m2;
    sx[row] = m2 * (1.f / 127.f);
  }
  __syncthreads();
  const float r = 127.f / bmax;
  #pragma unroll
  for (int j = 0; j < 4; ++j) {
    int a = __float2int_rn(v[j].x * r), b = __float2int_rn(v[j].y * r);
    int c = __float2int_rn(v[j].z * r), d = __float2int_rn(v[j].w * r);
    a = a > 127 ? 127 : (a < -127 ? -127 : a);
    b = b > 127 ? 127 : (b < -127 ? -127 : b);
    c = c > 127 ? 127 : (c < -127 ? -127 : c);
    d = d > 127 ? 127 : (d < -127 ? -127 : d);
    c4 q; q.x = (char)a; q.y = (char)b; q.z = (char)c; q.w = (char)d;
    *(c4*)(xq + (size_t)row * KDIM + j * 1024 + t * 4) = q;
  }
}

// --- Kernel 4: 128x256 i8 GEMM (16x16x64), 2 blk/CU, TRIPLE-buffer deep ledger ---
// [r17 BEST CONFIG, restored verbatim: 503.1us total / ~417us GEMM]
// C[m][n] = scale_w * sx[m] * (sum_k xq[m][k]*wq[n][k]) + bias[n]
// 3 LDS buffers x 24KB (72KB/block, 2x72=144<=160 keeps 2 blk/CU). 4 phases per
// K-tile; while computing buffer j, stage buffer j+2 (A@p0, B.h0@p1, B.h1@p2);
// VM(3)@p2 retires buffer j+1's 3 loads at age 4-6 phases (>= HBM latency) --
// never 0 in-loop (m201 property). 16x16x64 i8 MFMA; frag layout + 3-bit
// swizzle (0 conflicts); supertile grid (FETCH ~349MB); MFMA-first phases,
// 1 bar/phase; regs ~56+64acc.
// Buffer layout (24576B each): A:0..8191; B.h0:8192..16383; B.h1:16384..24575.
// Rotation: b_c (compute, K_i), b_n (next, K_i+1), b_s (stage tgt, K_i+2).
// Phases: p0: MFMA(L,01)@bc; load bq23(bc); stage A(bs)<-kS
//         p1: MFMA(L,23);    load afH(bc);  stage B.h0(bs)
//         p2: MFMA(H,01);    stage B.h1(bs); VM(3)
//         p3: MFMA(H,23);    load afL(bn)+bq01(bn)
// Ledger@p2-end: outstanding = bs{p0,p1,p2}(3) + bn{staged iter i-1}(3, ages
//   4-6 ph) -> VM(3) retires bn fully before p3's bn reads. Prologue stages
//   b0(3)+b1(3), VM(3) retires b0. WAR: every overwrite >= 3 barriers after
//   its region's reads issued, >= 2 after consumption. Tail: kS clamps to 63
//   (idempotent dup-stage; ledger exact). No other loop VMEM (no spill).

#define BAR()  __builtin_amdgcn_s_barrier()
#define SB0()  __builtin_amdgcn_sched_barrier(0)
#define PRIO1() __builtin_amdgcn_s_setprio(1)
#define PRIO0() __builtin_amdgcn_s_setprio(0)
#define VM(N)  asm volatile("s_waitcnt vmcnt(" #N ")" ::: "memory")

// One 8KB half-tile: 128 rows x 64 B; GROWB = global row base; LDSOFF runtime
#define STAGE(GP, GROWB, LDSOFF, KT) do {                                             \
  const char* _s = (GP) + (size_t)((GROWB) + srow) * KDIM + (KT)*64 + scol;           \
  char* _d = lds + (LDSOFF) + tid*16;                                                 \
  __builtin_amdgcn_global_load_lds((const GAS unsigned int*)_s,                       \
                                   (LAS unsigned int*)_d, 16, 0, 0);                  \
} while (0)

// B frag pair: DST[ni] covers output cols wn*64 + NH*32 + ni*16 + l15
#define LOAD_B2(DST, BASE, NH)                                                        \
  _Pragma("unroll") for (int ni = 0; ni < 2; ++ni)                                    \
    (DST)[ni] = *(const i32x4*)&lds[(BASE) + 8192 + bWOff + (NH)*2048 + ni*1024       \
                                    + rowoff + rcol];

// A frag pair: DST[mi] covers output rows wm*64 + MH*32 + mi*16 + l15
#define LOAD_A2(DST, BASE, MH)                                                        \
  _Pragma("unroll") for (int mi = 0; mi < 2; ++mi)                                    \
    (DST)[mi] = *(const i32x4*)&lds[(BASE) + aWOff + (MH)*2048 + mi*1024              \
                                    + rowoff + rcol];

// 4 MFMA (16x16x64 i8): 2 mi x 2 ni -> acc[MB+mi][NB+ni]
#define MFMA4(AF, MB, BQ, NB)                                                         \
  _Pragma("unroll") for (int mi = 0; mi < 2; ++mi)                                    \
  _Pragma("unroll") for (int ni = 0; ni < 2; ++ni)                                    \
    acc[(MB)+mi][(NB)+ni] = __builtin_amdgcn_mfma_i32_16x16x64_i8(                    \
        (AF)[mi], (BQ)[ni], acc[(MB)+mi][(NB)+ni], 0, 0, 0);

__global__ __launch_bounds__(512, 4) void k_gemm256(const char* __restrict__ A,
                                                    const char* __restrict__ B,
                                                    const float* __restrict__ bias,
                                                    const float* __restrict__ sx,
                                                    const float* __restrict__ scale_p,
                                                    float* __restrict__ C) {
  extern __shared__ char lds[];

  const int nTn = NDIM / 256;                  // 43
  const int nwg = (MDIM / 128) * nTn;          // 2752 (== 0 mod 8)
  int wg = (int)blockIdx.x;
  wg = (wg & 7) * (nwg / 8) + (wg >> 3);       // XCD-aware swizzle (bijective)
  // 8x8 super-tile order within each XCD band (L2 panel reuse)
  const int band = wg / (nTn * 8);             // 0..7
  const int rem  = wg % (nTn * 8);             // 0..343
  const int tn   = rem >> 3;                   // 0..42
  const int tm   = band * 8 + (rem & 7);       // 0..63

  const int tid  = (int)threadIdx.x;
  const int lane = tid & 63;
  const int wave = tid >> 6;                   // 0..7
  const int wm   = wave >> 2;                  // 0..1  (M)
  const int wn   = wave & 3;                   // 0..3  (N)
  const int l15  = lane & 15;

  // read-side (r13/r15/r17-verified): row = l15 (+16-mults), byte col swizzled
  const int rowoff = l15 * 64;
  const int rcol = ((lane >> 4) << 4) ^ (((l15 >> 1) & 3) << 4);
  // stage-side (verified involution): linear LDS dest; pre-swizzled global col
  const int srow = tid >> 2;                   // 0..127
  const int scol = ((tid & 3) << 4) ^ (((tid >> 3) & 3) << 4);

  const int aWOff = wm * 4096;                 // this wave's 64 A-rows (bytes)
  const int bWOff = wn * 4096;                 // this wave's 64 B-rows (bytes)
  const int aRow = tm * 128;
  const int bRow = tn * 256;

  i32x4 acc[4][4];
  #pragma unroll
  for (int i = 0; i < 4; ++i)
    #pragma unroll
    for (int j = 0; j < 4; ++j) acc[i][j] = i32x4{0, 0, 0, 0};

  i32x4 af[2], bq01[2], bq23[2];

  int b_c = 0, b_n = 24576, b_s = 49152;       // compute / next / stage bases

  // ---- prologue: b0{A,Bh0,Bh1}<-K0; b1{A,Bh0,Bh1}<-K1; VM(3) retires b0 ----
  STAGE(A, aRow,       0,             0);
  STAGE(B, bRow,       8192,          0);
  STAGE(B, bRow + 128, 16384,         0);
  STAGE(A, aRow,       24576,         1);
  STAGE(B, bRow,       24576 + 8192,  1);
  STAGE(B, bRow + 128, 24576 + 16384, 1);
  VM(3);
  SB0();
  BAR();
  LOAD_A2(af, 0, 0); LOAD_B2(bq01, 0, 0);      // operands for p0 (K0)

  #pragma unroll 1
  for (int i = 0; i < 64; ++i) {
    const int kS = (i + 2 > 63) ? 63 : i + 2;  // clamped tail (idempotent dup)
    // p0: MFMA(L,01)@bc; load bq23(bc); stage A(bs) <- kS
    PRIO1(); MFMA4(af, 0, bq01, 0); PRIO0(); SB0();
    LOAD_B2(bq23, b_c, 1);
    STAGE(A, aRow, b_s, kS);
    BAR();
    // p1: MFMA(L,23); load afH(bc) (WAR-pinned after MFMA); stage B.h0(bs)
    PRIO1(); MFMA4(af, 0, bq23, 2); PRIO0(); SB0();
    LOAD_A2(af, b_c, 1);
    STAGE(B, bRow, b_s + 8192, kS);
    BAR();
    // p2: MFMA(H,01); stage B.h1(bs); VM(3) retires b_n (ages 4-6 phases)
    PRIO1(); MFMA4(af, 2, bq01, 0); PRIO0(); SB0();
    STAGE(B, bRow + 128, b_s + 16384, kS);
    VM(3); SB0();
    BAR();
    // p3: MFMA(H,23); load afL(bn)+bq01(bn) for next iter's p0
    PRIO1(); MFMA4(af, 2, bq23, 2); PRIO0(); SB0();
    LOAD_A2(af, b_n, 0); LOAD_B2(bq01, b_n, 0);
    BAR();
    // rotate buffers
    const int t = b_c; b_c = b_n; b_n = b_s; b_s = t;
  }

  VM(0);  // drain tail dup-stages before epilogue

  const float sc = *scale_p;
  float bv[4];
  #pragma unroll
  for (int ni = 0; ni < 4; ++ni) bv[ni] = bias[tn * 256 + wn * 64 + ni * 16 + l15];

  // C/D layout (dtype-independent): col = lane&15, row = (lane>>4)*4 + reg
  #pragma unroll
  for (int mi = 0; mi < 4; ++mi) {
    #pragma unroll
    for (int r = 0; r < 4; ++r) {
      const int m = tm * 128 + wm * 64 + mi * 16 + (lane >> 4) * 4 + r;
      const float srow_scale = sc * sx[m];
      float* crow = C + (size_t)m * NDIM + tn * 256 + wn * 64;
      #pragma unroll
      for (int ni = 0; ni < 4; ++ni)
        crow[ni * 16 + l15] = srow_scale * (float)acc[mi][ni][r] + bv[ni];
    }
  }
}

extern "C" void kernel_launch(void* const* d_in, const int* in_sizes, int n_in,
                              void* d_out, int out_size, void* d_ws, size_t ws_size,
                              hipStream_t stream) {
  const float* x = (const float*)d_in[0];
  const float* w = (const float*)d_in[1];
  const float* bias = (const float*)d_in[2];
  float* out = (float*)d_out;

  char* ws = (char*)d_ws;
  const size_t XQ_BYTES = (size_t)MDIM * KDIM;   // 33,554,432
  const size_t WQ_BYTES = (size_t)NDIM * KDIM;   // 45,088,768
  char* xq = ws;
  char* wq = ws + XQ_BYTES;
  float* sx = (float*)(ws + XQ_BYTES + WQ_BYTES);
  float* partials = sx + MDIM;
  float* scale = partials + NBLK_W;

  k_convert_w<<<NBLK_W, 256, 0, stream>>>(w, wq, partials);
  k_scale<<<1, 256, 0, stream>>>(partials, scale);
  k_convert_x<<<MDIM, 256, 0, stream>>>(x, xq, sx);

  (void)hipFuncSetAttribute((const void*)k_gemm256,
                            hipFuncAttributeMaxDynamicSharedMemorySize, 73728);
  const int grid = (MDIM / 128) * (NDIM / 256);  // 2752
  k_gemm256<<<grid, 512, 73728, stream>>>(xq, wq, bias, sx, scale, out);
}